// Round 3
// baseline (63.597 us; speedup 1.0000x reference)
//
#include <hip/hip_runtime.h>

// mi = BETA * sum_d ( E[y_d^2] - (E[y_d])^2 )  over y: [1024, 256] fp32.
// Derivation: mean_i mean_j (y_jd - y_id)^2 = 2*Var_d; the /2 cancels.
//
// Cost structure (rocprof r1/r2): every iteration pays a fixed ~40.5 us
// harness poison-fill of the 256 MB ws (83% HBM peak — not ours).
// Residual ~16 us = graph overhead + our single kernel. This version
// shrinks kernel exec: 64 blocks (4x read parallelism), float4 input
// loads (1 KB/wave-instr, input is HBM-cold after the fill evicts
// L2 and exactly fills L3), compact 2 KB per-block partials via LDS
// reduce, float4 finisher fold.
//
// Single regular (graph-capturable) dispatch; fusion via init-free
// done-flags (ws is POISONED each iteration -> no zero-init counter):
//   block b>0: wave 0 writes 2 KB partial -> threadfence (release,
//     covers cross-XCD visibility) -> flag[b] = MAGIC (agent release).
//   block 0: spins on flags[1..63] (one per lane, parallel), fence
//     (acquire: invalidate stale L1), folds 64x2 KB, reduces, writes out.
// Poison resets flags every iteration; MAGIC is not a repeated-4-byte
// poison pattern. 64 blocks << 256 CUs -> co-resident, no deadlock.

#define N_ROWS 1024
#define D 256
#define NBLK 64
#define ROWS_PER_BLK (N_ROWS / NBLK)   // 16
#define BETA 0.001f
#define MAGIC 0x9E3779B97F4A7C15ULL

__global__ __launch_bounds__(256)
void club_onepass(const float* __restrict__ y,
                  float* __restrict__ ws,
                  float* __restrict__ out) {
    const int t  = threadIdx.x;        // 0..255
    const int b  = blockIdx.x;         // 0..63
    const int c  = t & 63;             // float4 column -> dims 4c..4c+3
    const int rg = t >> 6;             // row group (= wave id), 0..3
    unsigned long long* flags =
        (unsigned long long*)(ws + NBLK * 2 * D);   // at +128 KB, 8-aligned

    __shared__ float4 lsum[256];
    __shared__ float4 lsq[256];

    // ---- phase 1: each thread reads 4 rows x 1 float4 (wave reads a
    //      full 1 KB row per pass: 64 lanes x 16 B, perfectly coalesced)
    float4 S = {0.f, 0.f, 0.f, 0.f};
    float4 Q = {0.f, 0.f, 0.f, 0.f};
    {
        const float4* yp = (const float4*)(y + (size_t)b * ROWS_PER_BLK * D);
#pragma unroll
        for (int r = 0; r < 4; ++r) {
            float4 v = yp[(rg * 4 + r) * (D / 4) + c];
            S.x += v.x; S.y += v.y; S.z += v.z; S.w += v.w;
            Q.x += v.x * v.x; Q.y += v.y * v.y;
            Q.z += v.z * v.z; Q.w += v.w * v.w;
        }
    }
    lsum[t] = S; lsq[t] = Q;
    __syncthreads();

    // ---- LDS reduce 4 row-groups -> wave 0 holds per-dim block partial
    if (t < 64) {
        float4 a0 = lsum[t], a1 = lsum[t + 64], a2 = lsum[t + 128], a3 = lsum[t + 192];
        float4 q0 = lsq[t],  q1 = lsq[t + 64],  q2 = lsq[t + 128],  q3 = lsq[t + 192];
        float4 Ss = {a0.x + a1.x + a2.x + a3.x, a0.y + a1.y + a2.y + a3.y,
                     a0.z + a1.z + a2.z + a3.z, a0.w + a1.w + a2.w + a3.w};
        float4 Qs = {q0.x + q1.x + q2.x + q3.x, q0.y + q1.y + q2.y + q3.y,
                     q0.z + q1.z + q2.z + q3.z, q0.w + q1.w + q2.w + q3.w};
        ((float4*)(ws + (size_t)b * 2 * D))[c]            = Ss;  // s   [256]
        ((float4*)(ws + (size_t)b * 2 * D))[D / 4 + c]    = Qs;  // s^2 [256]
    }

    if (b != 0) {
        // publish: fence orders the partial stores (agent scope) before flag.
        __threadfence();
        __syncthreads();
        if (t == 0)
            __hip_atomic_store(&flags[b], (unsigned long long)MAGIC,
                               __ATOMIC_RELEASE, __HIP_MEMORY_SCOPE_AGENT);
        return;
    }

    // ---- finisher: block 0. Parallel spin: lane t waits on flags[t].
    if (t >= 1 && t < NBLK) {
        while (__hip_atomic_load(&flags[t], __ATOMIC_ACQUIRE,
                                 __HIP_MEMORY_SCOPE_AGENT) != MAGIC) { }
    }
    __syncthreads();
    __threadfence();   // acquire side: invalidate stale L1 before partial reads

    // fold 64 blocks x 2 KB with float4 loads; thread t covers dim-quad c
    // for block subset { g : g % 4 == rg }.
    float4 FS = {0.f, 0.f, 0.f, 0.f};
    float4 FQ = {0.f, 0.f, 0.f, 0.f};
    for (int g = rg; g < NBLK; g += 4) {
        const float4* ps = (const float4*)(ws + (size_t)g * 2 * D);
        float4 a = ps[c];
        float4 q = ps[D / 4 + c];
        FS.x += a.x; FS.y += a.y; FS.z += a.z; FS.w += a.w;
        FQ.x += q.x; FQ.y += q.y; FQ.z += q.z; FQ.w += q.w;
    }
    lsum[t] = FS; lsq[t] = FQ;
    __syncthreads();

    if (t < 64) {
        float4 a0 = lsum[t], a1 = lsum[t + 64], a2 = lsum[t + 128], a3 = lsum[t + 192];
        float4 q0 = lsq[t],  q1 = lsq[t + 64],  q2 = lsq[t + 128],  q3 = lsq[t + 192];
        float4 Ss = {a0.x + a1.x + a2.x + a3.x, a0.y + a1.y + a2.y + a3.y,
                     a0.z + a1.z + a2.z + a3.z, a0.w + a1.w + a2.w + a3.w};
        float4 Qs = {q0.x + q1.x + q2.x + q3.x, q0.y + q1.y + q2.y + q3.y,
                     q0.z + q1.z + q2.z + q3.z, q0.w + q1.w + q2.w + q3.w};
        const float invN = 1.0f / (float)N_ROWS;
        float4 mu  = {Ss.x * invN, Ss.y * invN, Ss.z * invN, Ss.w * invN};
        float4 var = {Qs.x * invN - mu.x * mu.x, Qs.y * invN - mu.y * mu.y,
                      Qs.z * invN - mu.z * mu.z, Qs.w * invN - mu.w * mu.w};
        float v = var.x + var.y + var.z + var.w;   // 4 dims per lane

        // wave(64)-level shuffle reduction over 64 lanes x 4 dims = 256 dims
#pragma unroll
        for (int off = 32; off > 0; off >>= 1)
            v += __shfl_down(v, off, 64);

        if (t == 0) out[0] = v * BETA;
    }
}

extern "C" void kernel_launch(void* const* d_in, const int* in_sizes, int n_in,
                              void* d_out, int out_size, void* d_ws, size_t ws_size,
                              hipStream_t stream) {
    const float* y = (const float*)d_in[0];
    float* ws = (float*)d_ws;          // uses NBLK*2*D*4 + NBLK*8 = ~128.5 KB
    float* out = (float*)d_out;

    club_onepass<<<NBLK, D, 0, stream>>>(y, ws, out);
}

// Round 4
// 55.695 us; speedup vs baseline: 1.1419x; 1.1419x over previous
//
#include <hip/hip_runtime.h>

// mi = BETA * sum_d ( E[y_d^2] - (E[y_d])^2 )  over y: [1024, 256] fp32.
// Derivation: mean_i mean_j (y_jd - y_id)^2 = 2*Var_d; the /2 cancels.
//
// Cost structure (rocprof r1-r3): every iteration pays a fixed ~40.5 us
// harness poison-fill of the 256 MB ws (83% HBM peak — not ours) plus
// ~16 us of fixed harness machinery (small reset fills + graph replay
// gaps). Dispatch count 2->1 moved nothing (56.3 vs 56.7); 64-block
// fan-in with per-thread device fences REGRESSED +7 us (cross-XCD
// buffer_wbl2 cost scales with publisher count). -> minimal shape:
// 16 blocks, single dispatch, ONE release-store per publisher block.
//
// Fusion via init-free done-flags (ws is POISONED each iteration, so no
// zero-init counter):
//   block b>0: accumulate -> LDS-fold -> wave 0 writes 2 KB partial ->
//     __syncthreads -> t0 agent-RELEASE store MAGIC to flags[b] (the
//     release store emits the L2 write-back once per block).
//   block 0: lanes 1..15 spin on flags (agent ACQUIRE), one acquire
//     fence, fold 16 x 2 KB partials (float4), reduce, write out.
// Poison resets flags each iteration; MAGIC is not a repeated-4-byte
// poison pattern. 16 blocks << 256 CUs -> co-resident, no deadlock.

#define N_ROWS 1024
#define D 256
#define NBLK 16
#define ROWS_PER_BLK (N_ROWS / NBLK)   // 64
#define BETA 0.001f
#define MAGIC 0x9E3779B97F4A7C15ULL

__global__ __launch_bounds__(256)
void club_onepass(const float* __restrict__ y,
                  float* __restrict__ ws,
                  float* __restrict__ out) {
    const int t  = threadIdx.x;        // 0..255
    const int b  = blockIdx.x;         // 0..15
    const int c  = t & 63;             // float4 column -> dims 4c..4c+3
    const int rg = t >> 6;             // wave id, 0..3
    unsigned long long* flags =
        (unsigned long long*)(ws + NBLK * 2 * D);   // at +32 KB, 8-aligned

    __shared__ float4 lsum[256];
    __shared__ float4 lsq[256];

    // ---- phase 1: block b covers rows [b*64, b*64+64).
    // Wave rg handles rows rg*16..rg*16+15; each pass the wave reads one
    // contiguous 1 KB row (64 lanes x float4). 16 float4 loads/thread.
    float4 S = {0.f, 0.f, 0.f, 0.f};
    float4 Q = {0.f, 0.f, 0.f, 0.f};
    {
        const float4* yp = (const float4*)(y + (size_t)b * ROWS_PER_BLK * D)
                           + (size_t)rg * 16 * (D / 4) + c;
#pragma unroll
        for (int r = 0; r < 16; ++r) {
            float4 v = yp[(size_t)r * (D / 4)];
            S.x += v.x; S.y += v.y; S.z += v.z; S.w += v.w;
            Q.x += v.x * v.x; Q.y += v.y * v.y;
            Q.z += v.z * v.z; Q.w += v.w * v.w;
        }
    }
    lsum[t] = S; lsq[t] = Q;
    __syncthreads();

    // ---- LDS fold: wave 0 combines the 4 waves -> per-dim block partial
    if (t < 64) {
        float4 a0 = lsum[t], a1 = lsum[t + 64], a2 = lsum[t + 128], a3 = lsum[t + 192];
        float4 q0 = lsq[t],  q1 = lsq[t + 64],  q2 = lsq[t + 128],  q3 = lsq[t + 192];
        float4 Ss = {a0.x + a1.x + a2.x + a3.x, a0.y + a1.y + a2.y + a3.y,
                     a0.z + a1.z + a2.z + a3.z, a0.w + a1.w + a2.w + a3.w};
        float4 Qs = {q0.x + q1.x + q2.x + q3.x, q0.y + q1.y + q2.y + q3.y,
                     q0.z + q1.z + q2.z + q3.z, q0.w + q1.w + q2.w + q3.w};
        ((float4*)(ws + (size_t)b * 2 * D))[c]         = Ss;  // sums   [256]
        ((float4*)(ws + (size_t)b * 2 * D))[D / 4 + c] = Qs;  // sumsqs [256]
    }
    __syncthreads();   // partial stores happen-before t0's release store

    if (b != 0) {
        if (t == 0)
            __hip_atomic_store(&flags[b], (unsigned long long)MAGIC,
                               __ATOMIC_RELEASE, __HIP_MEMORY_SCOPE_AGENT);
        return;
    }

    // ---- finisher: block 0. Parallel spin: lane t waits on flags[t].
    if (t >= 1 && t < NBLK) {
        while (__hip_atomic_load(&flags[t], __ATOMIC_ACQUIRE,
                                 __HIP_MEMORY_SCOPE_AGENT) != MAGIC) { }
    }
    __syncthreads();
    __threadfence();   // acquire: invalidate stale L1 before partial reads

    // fold 16 blocks x 2 KB; thread t covers dim-quad c for g%4==rg.
    float4 FS = {0.f, 0.f, 0.f, 0.f};
    float4 FQ = {0.f, 0.f, 0.f, 0.f};
#pragma unroll
    for (int g = rg; g < NBLK; g += 4) {
        const float4* ps = (const float4*)(ws + (size_t)g * 2 * D);
        float4 a = ps[c];
        float4 q = ps[D / 4 + c];
        FS.x += a.x; FS.y += a.y; FS.z += a.z; FS.w += a.w;
        FQ.x += q.x; FQ.y += q.y; FQ.z += q.z; FQ.w += q.w;
    }
    lsum[t] = FS; lsq[t] = FQ;
    __syncthreads();

    if (t < 64) {
        float4 a0 = lsum[t], a1 = lsum[t + 64], a2 = lsum[t + 128], a3 = lsum[t + 192];
        float4 q0 = lsq[t],  q1 = lsq[t + 64],  q2 = lsq[t + 128],  q3 = lsq[t + 192];
        float4 Ss = {a0.x + a1.x + a2.x + a3.x, a0.y + a1.y + a2.y + a3.y,
                     a0.z + a1.z + a2.z + a3.z, a0.w + a1.w + a2.w + a3.w};
        float4 Qs = {q0.x + q1.x + q2.x + q3.x, q0.y + q1.y + q2.y + q3.y,
                     q0.z + q1.z + q2.z + q3.z, q0.w + q1.w + q2.w + q3.w};
        const float invN = 1.0f / (float)N_ROWS;
        float4 mu  = {Ss.x * invN, Ss.y * invN, Ss.z * invN, Ss.w * invN};
        float4 var = {Qs.x * invN - mu.x * mu.x, Qs.y * invN - mu.y * mu.y,
                      Qs.z * invN - mu.z * mu.z, Qs.w * invN - mu.w * mu.w};
        float v = var.x + var.y + var.z + var.w;   // 4 dims per lane

        // wave(64)-level shuffle reduction: 64 lanes x 4 dims = 256 dims
#pragma unroll
        for (int off = 32; off > 0; off >>= 1)
            v += __shfl_down(v, off, 64);

        if (t == 0) out[0] = v * BETA;
    }
}

extern "C" void kernel_launch(void* const* d_in, const int* in_sizes, int n_in,
                              void* d_out, int out_size, void* d_ws, size_t ws_size,
                              hipStream_t stream) {
    const float* y = (const float*)d_in[0];
    float* ws = (float*)d_ws;          // uses NBLK*2*D*4 + NBLK*8 = ~32.1 KB
    float* out = (float*)d_out;

    club_onepass<<<NBLK, D, 0, stream>>>(y, ws, out);
}